// Round 1
// baseline (733.021 us; speedup 1.0000x reference)
//
#include <hip/hip_runtime.h>

#define NBATCH 8
#define LSEQ   4096
#define NHEAD  8
#define DCH    64
#define HEIGHT 64
#define WIDTH  64

#define KV_FLOATS   (NBATCH*NHEAD*DCH*DCH)   // 262144
#define KSUM_FLOATS (NBATCH*NHEAD*DCH)       // 4096

// ---------- helpers ----------
static __device__ __forceinline__ float bfu2f(unsigned short u) {
  return __uint_as_float(((unsigned int)u) << 16);
}
static __device__ __forceinline__ unsigned short f2bfu(float f) {
  unsigned int b = __float_as_uint(f);
  b += 0x7FFFu + ((b >> 16) & 1u);   // round-to-nearest-even
  return (unsigned short)(b >> 16);
}
// flag-dispatched float load: isbf wave-uniform
static __device__ __forceinline__ float ldf(const void* p, int i, int isbf) {
  return isbf ? bfu2f(((const unsigned short*)p)[i]) : ((const float*)p)[i];
}
static __device__ __forceinline__ float wave_sum64(float x) {
  #pragma unroll
  for (int m = 1; m < 64; m <<= 1) x += __shfl_xor(x, m, 64);
  return x;
}
// focused feature: x=(relu+1e-6)/scale ; f = x^3 * ||x|| / ||x^3||  (lane = d)
static __device__ __forceinline__ float focus_feat(float raw, float inv_scale) {
  float x  = (fmaxf(raw, 0.f) + 1e-6f) * inv_scale;
  float s2 = wave_sum64(x * x);
  float y  = x * x * x;
  float s6 = wave_sum64(y * y);
  return y * sqrtf(s2 / s6);
}

// ---------- dtype detection ----------
// bf16-packed data: low 16 bits of each dword are a valid bf16 of N(0,1)
// (exp field in [110,140] essentially always). fp32 data: low 16 bits are
// uniform mantissa bits (~12% hit rate). 256 samples separate cleanly.
__global__ void detect_kernel(const unsigned int* __restrict__ q, int* __restrict__ flag) {
  if (threadIdx.x == 0 && blockIdx.x == 0) {
    int hits = 0;
    for (int i = 0; i < 256; ++i) {
      unsigned int lo = q[i] & 0xFFFFu;
      unsigned int e  = (lo >> 7) & 0xFFu;
      if (lo == 0u || (e >= 110u && e <= 140u)) hits++;
    }
    *flag = (hits > 128) ? 1 : 0;
  }
}

// ---------- kernel B: kv[n,h,d,v] = sum_s kfeat[s,d]*V[s,v] ; ksum[n,h,d] ----------
#define CHUNKS      8
#define CHUNK_ROWS  512
#define SUB         64

__global__ __launch_bounds__(256) void kv_kernel(
    const void* __restrict__ keys, const void* __restrict__ values,
    const void* __restrict__ scale_param,
    float* __restrict__ kv_g, float* __restrict__ ksum_g,
    const int* __restrict__ flagp)
{
  __shared__ __align__(16) float kf_lds[SUB * DCH];
  __shared__ __align__(16) float vv_lds[SUB * DCH];
  __shared__ float red[4 * DCH];

  const int isbf = *flagp;
  const int b = blockIdx.x;
  const int chunk = b & 7;
  const int nh = b >> 3;            // nh = n*8 + h
  const int h = nh & 7, n = nh >> 3;
  const int t = threadIdx.x, lane = t & 63, wid = t >> 6;
  const int v = lane, g = wid;

  float sp = ldf(scale_param, lane, isbf);
  float scale = (sp > 20.f) ? sp : log1pf(expf(sp));  // softplus
  float inv_scale = 1.f / scale;

  float acc[16];
  #pragma unroll
  for (int i = 0; i < 16; ++i) acc[i] = 0.f;
  float ksum_acc = 0.f;

  for (int sub = 0; sub < CHUNK_ROWS / SUB; ++sub) {
    // feature phase: wave wid handles rows wid*16 .. wid*16+15 of this sub-batch
    for (int j = 0; j < 16; ++j) {
      int r = wid * 16 + j;
      int s = chunk * CHUNK_ROWS + sub * SUB + r;
      int gi = ((n * LSEQ + s) * NHEAD + h) * DCH + lane;
      float f = focus_feat(ldf(keys, gi, isbf), inv_scale);
      kf_lds[r * DCH + lane] = f;
      ksum_acc += f;
      vv_lds[r * DCH + lane] = ldf(values, gi, isbf);
    }
    __syncthreads();
    // accumulate phase: thread owns kv[g*16 .. g*16+15][v]
    for (int s = 0; s < SUB; ++s) {
      float vval = vv_lds[s * DCH + v];
      const float4* kf4 = (const float4*)&kf_lds[s * DCH + g * 16];
      float4 a0 = kf4[0], a1 = kf4[1], a2 = kf4[2], a3 = kf4[3];
      acc[0]  += a0.x * vval; acc[1]  += a0.y * vval;
      acc[2]  += a0.z * vval; acc[3]  += a0.w * vval;
      acc[4]  += a1.x * vval; acc[5]  += a1.y * vval;
      acc[6]  += a1.z * vval; acc[7]  += a1.w * vval;
      acc[8]  += a2.x * vval; acc[9]  += a2.y * vval;
      acc[10] += a2.z * vval; acc[11] += a2.w * vval;
      acc[12] += a3.x * vval; acc[13] += a3.y * vval;
      acc[14] += a3.z * vval; acc[15] += a3.w * vval;
    }
    __syncthreads();
  }

  #pragma unroll
  for (int i = 0; i < 16; ++i)
    atomicAdd(&kv_g[nh * (DCH * DCH) + (g * 16 + i) * DCH + v], acc[i]);

  red[wid * 64 + lane] = ksum_acc;
  __syncthreads();
  if (t < 64) {
    float tot = red[lane] + red[64 + lane] + red[128 + lane] + red[192 + lane];
    atomicAdd(&ksum_g[nh * DCH + lane], tot);
  }
}

// ---------- kernel C: per (n,h,y): o = qfeat·kv·z  +  dwconv5x5(V) + bias ----------
__global__ __launch_bounds__(256) void out_kernel(
    const void* __restrict__ queries, const void* __restrict__ values,
    const void* __restrict__ scale_param, const void* __restrict__ dwc_w,
    const void* __restrict__ dwc_b,
    const float* __restrict__ kv_g, const float* __restrict__ ksum_g,
    void* __restrict__ out, const int* __restrict__ flagp)
{
  __shared__ __align__(16) float kv_lds[DCH * DCH];           // 16 KB
  __shared__ __align__(16) float qf_lds[WIDTH * DCH];         // 16 KB
  __shared__ __align__(16) unsigned short v_lds[5 * WIDTH * DCH]; // 40 KB (bf16)
  __shared__ float w_lds[DCH * 25];                           // 6.4 KB
  __shared__ float bias_lds[DCH];
  __shared__ float ksum_lds[DCH];
  __shared__ float z_lds[WIDTH];

  const int isbf = *flagp;
  const int b = blockIdx.x;
  const int y = b & 63;
  const int nh = b >> 6;
  const int h = nh & 7, n = nh >> 3;
  const int t = threadIdx.x, lane = t & 63, wid = t >> 6;
  const int v = lane, g = wid;

  // ---- staging ----
  for (int i = t; i < DCH * DCH; i += 256) kv_lds[i] = kv_g[nh * (DCH * DCH) + i];
  for (int i = t; i < DCH * 25; i += 256)  w_lds[i] = ldf(dwc_w, i, isbf);
  if (t < DCH) {
    bias_lds[t] = ldf(dwc_b, t, isbf);
    ksum_lds[t] = ksum_g[nh * DCH + t];
  }
  // stage 5 value rows (y-2..y+2), zero-padded, as bf16
  for (int idx = t; idx < 5 * WIDTH * 8; idx += 256) {
    int p = idx >> 3, j = idx & 7;          // pixel, 8-elem group
    int ky = p >> 6, xx = p & 63;
    int yy = y - 2 + ky;
    unsigned short* dst = &v_lds[(ky * WIDTH + xx) * DCH + j * 8];
    if (yy >= 0 && yy < HEIGHT) {
      int gi = ((n * LSEQ + yy * WIDTH + xx) * NHEAD + h) * DCH + j * 8;
      if (isbf) {
        *(uint4*)dst = *(const uint4*)((const unsigned short*)values + gi);
      } else {
        const float4* s4 = (const float4*)((const float*)values + gi);
        float4 f0 = s4[0], f1 = s4[1];
        dst[0] = f2bfu(f0.x); dst[1] = f2bfu(f0.y);
        dst[2] = f2bfu(f0.z); dst[3] = f2bfu(f0.w);
        dst[4] = f2bfu(f1.x); dst[5] = f2bfu(f1.y);
        dst[6] = f2bfu(f1.z); dst[7] = f2bfu(f1.w);
      }
    } else {
      uint4 z; z.x = z.y = z.z = z.w = 0u;
      *(uint4*)dst = z;
    }
  }
  __syncthreads();

  // ---- q features + z: wave wid handles x = wid*16 .. wid*16+15, lane = d ----
  {
    float sp = ldf(scale_param, lane, isbf);
    float scale = (sp > 20.f) ? sp : log1pf(expf(sp));
    float inv_scale = 1.f / scale;
    for (int xi = 0; xi < 16; ++xi) {
      int x = wid * 16 + xi;
      int gi = ((n * LSEQ + y * WIDTH + x) * NHEAD + h) * DCH + lane;
      float f = focus_feat(ldf(queries, gi, isbf), inv_scale);
      qf_lds[x * DCH + lane] = f;
      float dot = wave_sum64(f * ksum_lds[lane]);
      if (lane == 0) z_lds[x] = 1.f / (dot + 1e-6f);
    }
  }
  __syncthreads();

  // ---- compute: thread owns channel v, x in {g, g+4, ..., g+60} ----
  float kvc[64];
  #pragma unroll
  for (int d = 0; d < 64; ++d) kvc[d] = kv_lds[d * DCH + v];
  float wr[25];
  #pragma unroll
  for (int k = 0; k < 25; ++k) wr[k] = w_lds[v * 25 + k];
  const float bv = bias_lds[v];

  for (int ii = 0; ii < 16; ++ii) {
    int x = g + 4 * ii;
    // o = qf[x,:] . kv[:,v]
    float o = 0.f;
    const float4* q4 = (const float4*)&qf_lds[x * DCH];
    #pragma unroll
    for (int d4 = 0; d4 < 16; ++d4) {
      float4 qv = q4[d4];
      o += qv.x * kvc[4 * d4 + 0] + qv.y * kvc[4 * d4 + 1]
         + qv.z * kvc[4 * d4 + 2] + qv.w * kvc[4 * d4 + 3];
    }
    float res = o * z_lds[x] + bv;
    // depthwise 5x5 conv (rows already zero-padded; x handled here)
    #pragma unroll
    for (int ky = 0; ky < 5; ++ky) {
      #pragma unroll
      for (int kx = 0; kx < 5; ++kx) {
        int xx = x - 2 + kx;
        if ((unsigned)xx < (unsigned)WIDTH) {
          float vv = bfu2f(v_lds[(ky * WIDTH + xx) * DCH + v]);
          res += wr[ky * 5 + kx] * vv;
        }
      }
    }
    int oi = ((n * LSEQ + y * WIDTH + x) * NHEAD + h) * DCH + v;
    if (isbf) ((unsigned short*)out)[oi] = f2bfu(res);
    else      ((float*)out)[oi] = res;
  }
}

// ---------- launch ----------
extern "C" void kernel_launch(void* const* d_in, const int* in_sizes, int n_in,
                              void* d_out, int out_size, void* d_ws, size_t ws_size,
                              hipStream_t stream) {
  // inputs: 0=queries 1=keys 2=values 3=scale_param 4=dwc_w 5=dwc_b 6=height
  float* kv_g   = (float*)d_ws;
  float* ksum_g = kv_g + KV_FLOATS;
  int*   flag   = (int*)(ksum_g + KSUM_FLOATS);

  hipMemsetAsync(d_ws, 0, (size_t)(KV_FLOATS + KSUM_FLOATS) * sizeof(float), stream);
  detect_kernel<<<1, 64, 0, stream>>>((const unsigned int*)d_in[0], flag);
  kv_kernel<<<dim3(NBATCH * NHEAD * CHUNKS), dim3(256), 0, stream>>>(
      d_in[1], d_in[2], d_in[3], kv_g, ksum_g, flag);
  out_kernel<<<dim3(NBATCH * NHEAD * HEIGHT), dim3(256), 0, stream>>>(
      d_in[0], d_in[2], d_in[3], d_in[4], d_in[5], kv_g, ksum_g, d_out, flag);
}

// Round 2
// 400.586 us; speedup vs baseline: 1.8299x; 1.8299x over previous
//
#include <hip/hip_runtime.h>

typedef __attribute__((ext_vector_type(8))) short short8;
typedef __attribute__((ext_vector_type(4))) float f32x4;

#define LSEQ   4096
#define NHEAD  8
#define DCH    64
#define HEIGHT 64
#define WIDTH  64

// ---------- helpers ----------
static __device__ __forceinline__ float bfu2f(unsigned short u) {
  return __uint_as_float(((unsigned int)u) << 16);
}
static __device__ __forceinline__ unsigned short f2bfu(float f) {
  unsigned int b = __float_as_uint(f);
  b += 0x7FFFu + ((b >> 16) & 1u);   // RNE
  return (unsigned short)(b >> 16);
}
static __device__ __forceinline__ float ldf(const void* p, int i, int isbf) {
  return isbf ? bfu2f(((const unsigned short*)p)[i]) : ((const float*)p)[i];
}
static __device__ __forceinline__ float wave_sum64(float x) {
  #pragma unroll
  for (int m = 1; m < 64; m <<= 1) x += __shfl_xor(x, m, 64);
  return x;
}
static __device__ __forceinline__ float softplus_inv(float sp) {
  float s = (sp > 20.f) ? sp : log1pf(expf(sp));
  return 1.f / s;
}
// focused feature (lane = d): x=(relu+1e-6)*inv_scale ; f = x^3 * sqrt(sum x^2 / sum x^6)
static __device__ __forceinline__ float focus_feat(float raw, float inv_scale) {
  float x  = (fmaxf(raw, 0.f) + 1e-6f) * inv_scale;
  float s2 = wave_sum64(x * x);
  float y  = x * x * x;
  float s6 = wave_sum64(y * y);
  return y * sqrtf(s2 / s6);
}
static __device__ __forceinline__ void unpack2(unsigned int u, float& lo, float& hi) {
  lo = __uint_as_float(u << 16);
  hi = __uint_as_float(u & 0xFFFF0000u);
}

// ---------- dtype detection (parallel) ----------
__global__ void detect_kernel(const unsigned int* __restrict__ q, int* __restrict__ flag) {
  int lane = threadIdx.x & 63;
  int hits = 0;
  #pragma unroll
  for (int i = 0; i < 4; ++i) {
    unsigned int lo = q[lane * 4 + i] & 0xFFFFu;
    unsigned int e  = (lo >> 7) & 0xFFu;
    if (lo == 0u || (e >= 110u && e <= 140u)) hits++;
  }
  #pragma unroll
  for (int m = 1; m < 64; m <<= 1) hits += __shfl_xor(hits, m, 64);
  if (lane == 0) *flag = (hits > 128) ? 1 : 0;
}

// ---------- kv kernel: MFMA partial kv per chunk; ksum via block-reduced atomics ----
// kf_t / vv_t: transposed tiles [64 ch][40 s-pad] bf16 (row stride 80 B, 16B-aligned)
__global__ __launch_bounds__(256) void kv_kernel(
    const void* __restrict__ keys, const void* __restrict__ values,
    const void* __restrict__ scale_param,
    float* __restrict__ kv_p, float* __restrict__ ksum_g,
    const int* __restrict__ flagp, int chunks, int rows)
{
  __shared__ __align__(16) unsigned short kf_t[64 * 40];
  __shared__ __align__(16) unsigned short vv_t[64 * 40];
  __shared__ float red[256];

  const int isbf = *flagp;
  const int b = blockIdx.x;
  const int chunk = b % chunks;
  const int nh = b / chunks;
  const int h = nh & 7, n = nh >> 3;
  const int t = threadIdx.x, lane = t & 63, wid = t >> 6;
  const int quad = lane >> 4, m16 = lane & 15;

  const float inv_scale = softplus_inv(ldf(scale_param, lane, isbf));

  f32x4 acc[4];
  #pragma unroll
  for (int mt = 0; mt < 4; ++mt) acc[mt] = (f32x4){0.f, 0.f, 0.f, 0.f};
  float ksum_acc = 0.f;

  const int nsub = rows >> 5;
  for (int sub = 0; sub < nsub; ++sub) {
    const int s_base = chunk * rows + sub * 32;
    // feature + transpose staging: 8 rows per wave, lane = channel
    #pragma unroll
    for (int j = 0; j < 8; ++j) {
      int sl = wid * 8 + j;               // 0..31
      int s = s_base + sl;
      int gi = ((n * LSEQ + s) * NHEAD + h) * DCH + lane;
      float kf = focus_feat(ldf(keys, gi, isbf), inv_scale);
      ksum_acc += kf;
      kf_t[lane * 40 + sl] = f2bfu(kf);
      vv_t[lane * 40 + sl] = isbf ? ((const unsigned short*)values)[gi]
                                  : f2bfu(((const float*)values)[gi]);
    }
    __syncthreads();
    // MFMA: D[d][v] += kf_t[d][s] * vv_t[v][s] ; wave owns v-slice wid*16..+15
    short8 bfr = *(const short8*)&vv_t[(wid * 16 + m16) * 40 + quad * 8];
    #pragma unroll
    for (int mt = 0; mt < 4; ++mt) {
      short8 afr = *(const short8*)&kf_t[(mt * 16 + m16) * 40 + quad * 8];
      acc[mt] = __builtin_amdgcn_mfma_f32_16x16x32_bf16(afr, bfr, acc[mt], 0, 0, 0);
    }
    __syncthreads();
  }

  // write fp32 partials: kv_p[chunk][nh][d][v]
  float* dst = kv_p + ((size_t)chunk * 64 + nh) * 4096;
  #pragma unroll
  for (int mt = 0; mt < 4; ++mt)
    #pragma unroll
    for (int r = 0; r < 4; ++r) {
      int d = mt * 16 + quad * 4 + r;
      dst[d * 64 + wid * 16 + m16] = acc[mt][r];
    }

  // ksum block reduce -> one atomic per d
  red[t] = ksum_acc;
  __syncthreads();
  if (t < 64) {
    float tot = red[t] + red[64 + t] + red[128 + t] + red[192 + t];
    atomicAdd(&ksum_g[nh * 64 + t], tot);
  }
}

// ---------- reduce: sum chunks, emit kv as bf16 [nh][v][d] (B-frag friendly) ----
__global__ __launch_bounds__(256) void reduce_kernel(
    const float* __restrict__ kv_p, unsigned short* __restrict__ kvb, int chunks)
{
  int c = blockIdx.x * 256 + threadIdx.x;   // 0..262143
  int nh = c >> 12;
  int dv = c & 4095;
  int d = dv >> 6, v = dv & 63;
  float s = 0.f;
  for (int ch = 0; ch < chunks; ++ch)
    s += kv_p[((size_t)ch * 64 + nh) * 4096 + dv];
  kvb[(nh * 64 + v) * 64 + d] = f2bfu(s);
}

// ---------- attention kernel: per (n,h,y) MFMA O = (qf*z) @ kv ----------
__global__ __launch_bounds__(256) void attn_kernel(
    const void* __restrict__ queries, const unsigned short* __restrict__ kvb,
    const float* __restrict__ ksum_g, const void* __restrict__ scale_param,
    void* __restrict__ out, const int* __restrict__ flagp)
{
  __shared__ __align__(16) unsigned short qf[64 * 72];  // row stride 144 B

  const int isbf = *flagp;
  const int b = blockIdx.x;
  const int y = b & 63;
  const int nh = b >> 6;
  const int h = nh & 7, n = nh >> 3;
  const int t = threadIdx.x, lane = t & 63, wid = t >> 6;
  const int quad = lane >> 4, m16 = lane & 15;

  const float inv_scale = softplus_inv(ldf(scale_param, lane, isbf));
  const float ks = ksum_g[nh * 64 + lane];

  // B fragments straight from global (L2-resident: 8 KB per (n,h))
  const unsigned short* kvrow = kvb + (nh * 64 + wid * 16 + m16) * 64;
  short8 bfr0 = *(const short8*)&kvrow[quad * 8];
  short8 bfr1 = *(const short8*)&kvrow[32 + quad * 8];

  // features: wave wid computes rows x = wid*16..+15 ; fold z into qf
  for (int xi = 0; xi < 16; ++xi) {
    int x = wid * 16 + xi;
    int gi = ((n * LSEQ + y * 64 + x) * NHEAD + h) * DCH + lane;
    float f = focus_feat(ldf(queries, gi, isbf), inv_scale);
    float dot = wave_sum64(f * ks);
    float z = 1.f / (dot + 1e-6f);
    qf[x * 72 + lane] = f2bfu(f * z);
  }
  __syncthreads();

  const size_t obase = (((size_t)n * LSEQ + y * 64) * NHEAD + h) * DCH;
  #pragma unroll
  for (int mt = 0; mt < 4; ++mt) {
    f32x4 acc = (f32x4){0.f, 0.f, 0.f, 0.f};
    short8 a0 = *(const short8*)&qf[(mt * 16 + m16) * 72 + quad * 8];
    short8 a1 = *(const short8*)&qf[(mt * 16 + m16) * 72 + 32 + quad * 8];
    acc = __builtin_amdgcn_mfma_f32_16x16x32_bf16(a0, bfr0, acc, 0, 0, 0);
    acc = __builtin_amdgcn_mfma_f32_16x16x32_bf16(a1, bfr1, acc, 0, 0, 0);
    #pragma unroll
    for (int r = 0; r < 4; ++r) {
      int x = mt * 16 + quad * 4 + r;
      int v = wid * 16 + m16;
      size_t oi = obase + (size_t)x * (NHEAD * DCH) + v;
      if (isbf) ((unsigned short*)out)[oi] = f2bfu(acc[r]);
      else      ((float*)out)[oi] = acc[r];
    }
  }
}

// ---------- conv kernel: depthwise 5x5 + bias, RMW on out ----------
// slab of 4 output rows; vs[8 rows][64 x][64 ch] bf16 with XOR-swizzled 8ch groups
__global__ __launch_bounds__(256) void conv_kernel(
    const void* __restrict__ values, const void* __restrict__ dwc_w,
    const void* __restrict__ dwc_b, void* __restrict__ out,
    const int* __restrict__ flagp)
{
  __shared__ __align__(16) unsigned short vs[8 * 64 * 64];  // 64 KB
  __shared__ float wl[25 * 64];                              // [tap][ch]
  __shared__ float bl[64];

  const int isbf = *flagp;
  const int b = blockIdx.x;
  const int slab = b & 15;
  const int nh = b >> 4;
  const int h = nh & 7, n = nh >> 3;
  const int y0 = slab * 4;
  const int t = threadIdx.x;

  for (int i = t; i < 25 * 64; i += 256) {
    int d = i / 25, tap = i - d * 25;
    wl[tap * 64 + d] = ldf(dwc_w, i, isbf);
  }
  if (t < 64) bl[t] = ldf(dwc_b, t, isbf);

  // stage rows y0-2 .. y0+5 (zero-padded), swizzle group j ^= (x&7)
  for (int it = t; it < 8 * 64 * 8; it += 256) {
    int j = it & 7;
    int xx = (it >> 3) & 63;
    int rr = it >> 9;                    // 0..7
    int yy = y0 - 2 + rr;
    unsigned short* dst = &vs[((rr * 64 + xx) * 64) + ((j ^ (xx & 7)) * 8)];
    if (yy >= 0 && yy < HEIGHT) {
      int gi = ((n * LSEQ + yy * 64 + xx) * NHEAD + h) * DCH + j * 8;
      if (isbf) {
        *(uint4*)dst = *(const uint4*)((const unsigned short*)values + gi);
      } else {
        const float4* s4 = (const float4*)((const float*)values + gi);
        float4 f0 = s4[0], f1 = s4[1];
        dst[0] = f2bfu(f0.x); dst[1] = f2bfu(f0.y);
        dst[2] = f2bfu(f0.z); dst[3] = f2bfu(f0.w);
        dst[4] = f2bfu(f1.x); dst[5] = f2bfu(f1.y);
        dst[6] = f2bfu(f1.z); dst[7] = f2bfu(f1.w);
      }
    } else {
      uint4 z; z.x = z.y = z.z = z.w = 0u;
      *(uint4*)dst = z;
    }
  }
  __syncthreads();

  const int xx = t & 63, jb = t >> 6;
  for (int jj = jb; jj < 8; jj += 4) {
    float a[4][8];
    float bias8[8];
    {
      float4 b0 = *(const float4*)&bl[jj * 8];
      float4 b1 = *(const float4*)&bl[jj * 8 + 4];
      bias8[0]=b0.x; bias8[1]=b0.y; bias8[2]=b0.z; bias8[3]=b0.w;
      bias8[4]=b1.x; bias8[5]=b1.y; bias8[6]=b1.z; bias8[7]=b1.w;
    }
    #pragma unroll
    for (int r = 0; r < 4; ++r)
      #pragma unroll
      for (int c = 0; c < 8; ++c) a[r][c] = bias8[c];

    for (int ky = 0; ky < 5; ++ky) {
      #pragma unroll
      for (int kx = 0; kx < 5; ++kx) {
        int xs = xx + kx - 2;
        if ((unsigned)xs < (unsigned)WIDTH) {
          float4 w0 = *(const float4*)&wl[(ky * 5 + kx) * 64 + jj * 8];
          float4 w1 = *(const float4*)&wl[(ky * 5 + kx) * 64 + jj * 8 + 4];
          #pragma unroll
          for (int r = 0; r < 4; ++r) {
            uint4 pv = *(const uint4*)&vs[(((r + ky) * 64 + xs) * 64) + ((jj ^ (xs & 7)) * 8)];
            float v0,v1,v2,v3,v4,v5,v6,v7;
            unpack2(pv.x, v0, v1); unpack2(pv.y, v2, v3);
            unpack2(pv.z, v4, v5); unpack2(pv.w, v6, v7);
            a[r][0] += w0.x * v0; a[r][1] += w0.y * v1;
            a[r][2] += w0.z * v2; a[r][3] += w0.w * v3;
            a[r][4] += w1.x * v4; a[r][5] += w1.y * v5;
            a[r][6] += w1.z * v6; a[r][7] += w1.w * v7;
          }
        }
      }
    }
    // RMW out
    #pragma unroll
    for (int r = 0; r < 4; ++r) {
      size_t oi = (((size_t)n * LSEQ + (y0 + r) * 64 + xx) * NHEAD + h) * DCH + jj * 8;
      if (isbf) {
        unsigned short* op = (unsigned short*)out + oi;
        uint4 cur = *(uint4*)op;
        float c0,c1,c2,c3,c4,c5,c6,c7;
        unpack2(cur.x, c0, c1); unpack2(cur.y, c2, c3);
        unpack2(cur.z, c4, c5); unpack2(cur.w, c6, c7);
        uint4 res;
        res.x = (unsigned int)f2bfu(c0 + a[r][0]) | ((unsigned int)f2bfu(c1 + a[r][1]) << 16);
        res.y = (unsigned int)f2bfu(c2 + a[r][2]) | ((unsigned int)f2bfu(c3 + a[r][3]) << 16);
        res.z = (unsigned int)f2bfu(c4 + a[r][4]) | ((unsigned int)f2bfu(c5 + a[r][5]) << 16);
        res.w = (unsigned int)f2bfu(c6 + a[r][6]) | ((unsigned int)f2bfu(c7 + a[r][7]) << 16);
        *(uint4*)op = res;
      } else {
        float* op = (float*)out + oi;
        float4 o0 = *(float4*)op;
        float4 o1 = *(float4*)(op + 4);
        o0.x += a[r][0]; o0.y += a[r][1]; o0.z += a[r][2]; o0.w += a[r][3];
        o1.x += a[r][4]; o1.y += a[r][5]; o1.z += a[r][6]; o1.w += a[r][7];
        *(float4*)op = o0;
        *(float4*)(op + 4) = o1;
      }
    }
  }
}

// ---------- launch ----------
extern "C" void kernel_launch(void* const* d_in, const int* in_sizes, int n_in,
                              void* d_out, int out_size, void* d_ws, size_t ws_size,
                              hipStream_t stream) {
  // inputs: 0=queries 1=keys 2=values 3=scale_param 4=dwc_w 5=dwc_b 6=height
  int chunks = 16;
  while (chunks > 1) {
    size_t need = (size_t)chunks * 64 * 4096 * 4 + 64 * 4096 * 2 + 4096 * 4 + 64;
    if (need <= ws_size) break;
    chunks >>= 1;
  }
  const int rows = LSEQ / chunks;

  float* kv_p = (float*)d_ws;
  unsigned short* kvb = (unsigned short*)(kv_p + (size_t)chunks * 64 * 4096);
  float* ksum = (float*)(kvb + 64 * 4096);
  int* flag = (int*)(ksum + 4096);

  hipMemsetAsync(ksum, 0, 4096 * sizeof(float), stream);
  detect_kernel<<<1, 64, 0, stream>>>((const unsigned int*)d_in[0], flag);
  kv_kernel<<<64 * chunks, 256, 0, stream>>>(
      d_in[1], d_in[2], d_in[3], kv_p, ksum, flag, chunks, rows);
  reduce_kernel<<<1024, 256, 0, stream>>>(kv_p, kvb, chunks);
  attn_kernel<<<NHEAD * 8 * HEIGHT / 1, 256, 0, stream>>>(  // 4096 blocks
      d_in[0], kvb, ksum, d_in[3], d_out, flag);
  conv_kernel<<<64 * 16, 256, 0, stream>>>(
      d_in[2], d_in[4], d_in[5], d_out, flag);
}

// Round 3
// 334.076 us; speedup vs baseline: 2.1942x; 1.1991x over previous
//
#include <hip/hip_runtime.h>

typedef __attribute__((ext_vector_type(8))) short short8;
typedef __attribute__((ext_vector_type(4))) float f32x4;

#define LSEQ   4096
#define NHEAD  8
#define DCH    64
#define HEIGHT 64
#define WIDTH  64

// ---------- helpers ----------
static __device__ __forceinline__ float bfu2f(unsigned short u) {
  return __uint_as_float(((unsigned int)u) << 16);
}
static __device__ __forceinline__ unsigned short f2bfu(float f) {
  unsigned int b = __float_as_uint(f);
  b += 0x7FFFu + ((b >> 16) & 1u);   // RNE
  return (unsigned short)(b >> 16);
}
static __device__ __forceinline__ float ldf(const void* p, int i, int isbf) {
  return isbf ? bfu2f(((const unsigned short*)p)[i]) : ((const float*)p)[i];
}
static __device__ __forceinline__ float softplus_inv(float sp) {
  float s = (sp > 20.f) ? sp : log1pf(expf(sp));
  return 1.f / s;
}
static __device__ __forceinline__ void unpack2(unsigned int u, float& lo, float& hi) {
  lo = __uint_as_float(u << 16);
  hi = __uint_as_float(u & 0xFFFF0000u);
}
// load 8 consecutive channels as floats (b128 for bf16, 2x b128 for fp32)
static __device__ __forceinline__ void load8(const void* p, int gi, int isbf, float o[8]) {
  if (isbf) {
    uint4 u = *(const uint4*)((const unsigned short*)p + gi);
    unpack2(u.x, o[0], o[1]); unpack2(u.y, o[2], o[3]);
    unpack2(u.z, o[4], o[5]); unpack2(u.w, o[6], o[7]);
  } else {
    const float4* f4 = (const float4*)((const float*)p + gi);
    float4 a = f4[0], b = f4[1];
    o[0]=a.x; o[1]=a.y; o[2]=a.z; o[3]=a.w;
    o[4]=b.x; o[5]=b.y; o[6]=b.z; o[7]=b.w;
  }
}
// reduce over the 8 lanes sharing a row (xor masks 1,2,4)
static __device__ __forceinline__ void row_reduce2(float& a, float& b) {
  #pragma unroll
  for (int m = 1; m < 8; m <<= 1) { a += __shfl_xor(a, m, 64); b += __shfl_xor(b, m, 64); }
}
static __device__ __forceinline__ float row_reduce1(float a) {
  #pragma unroll
  for (int m = 1; m < 8; m <<= 1) a += __shfl_xor(a, m, 64);
  return a;
}

// ---------- dtype detection ----------
__global__ void detect_kernel(const unsigned int* __restrict__ q, int* __restrict__ flag) {
  int lane = threadIdx.x & 63;
  int hits = 0;
  #pragma unroll
  for (int i = 0; i < 4; ++i) {
    unsigned int lo = q[lane * 4 + i] & 0xFFFFu;
    unsigned int e  = (lo >> 7) & 0xFFu;
    if (lo == 0u || (e >= 110u && e <= 140u)) hits++;
  }
  #pragma unroll
  for (int m = 1; m < 64; m <<= 1) hits += __shfl_xor(hits, m, 64);
  if (lane == 0) *flag = (hits > 128) ? 1 : 0;
}

// ---------- kv kernel ----------
// Stage 32 rows/sub; lane = (row r, chan-chunk c). Transposed LDS [d][s'] with
// s' = s ^ (((d>>3)&3)<<3): scatter b16 writes ~2-way conflicts, frag reads are
// 16B-aligned b128 (bank-uniform). MFMA D[d][v] += kf[s,d]*vv[s,v].
__global__ __launch_bounds__(256) void kv_kernel(
    const void* __restrict__ keys, const void* __restrict__ values,
    const void* __restrict__ scale_param,
    float* __restrict__ kv_p, float* __restrict__ ksum_g,
    const int* __restrict__ flagp, int chunks, int rows)
{
  __shared__ __align__(16) unsigned short kfT[64 * 40];
  __shared__ __align__(16) unsigned short vvT[64 * 40];
  __shared__ float red[256];

  const int isbf = *flagp;
  const int b = blockIdx.x;
  const int chunk = b % chunks;
  const int nh = b / chunks;
  const int h = nh & 7, n = nh >> 3;
  const int t = threadIdx.x, lane = t & 63, wid = t >> 6;
  const int quad = lane >> 4, m16 = lane & 15;
  const int r = lane >> 3, c = lane & 7, d0 = c * 8;
  const int s_local = wid * 8 + r;
  const int sp = s_local ^ ((c & 3) << 3);

  float inv_s[8];
  #pragma unroll
  for (int i = 0; i < 8; ++i) inv_s[i] = softplus_inv(ldf(scale_param, d0 + i, isbf));

  f32x4 acc[4];
  #pragma unroll
  for (int mt = 0; mt < 4; ++mt) acc[mt] = (f32x4){0.f, 0.f, 0.f, 0.f};
  float ksum_acc[8];
  #pragma unroll
  for (int i = 0; i < 8; ++i) ksum_acc[i] = 0.f;

  const int nsub = rows >> 5;
  for (int sub = 0; sub < nsub; ++sub) {
    const int s = chunk * rows + sub * 32 + s_local;
    const int gi = ((n * LSEQ + s) * NHEAD + h) * DCH + d0;

    float kraw[8];
    load8(keys, gi, isbf, kraw);
    float xv[8], yv[8], s2 = 0.f, s6 = 0.f;
    #pragma unroll
    for (int i = 0; i < 8; ++i) {
      xv[i] = (fmaxf(kraw[i], 0.f) + 1e-6f) * inv_s[i];
      s2 += xv[i] * xv[i];
    }
    #pragma unroll
    for (int i = 0; i < 8; ++i) {
      yv[i] = xv[i] * xv[i] * xv[i];
      s6 += yv[i] * yv[i];
    }
    row_reduce2(s2, s6);
    const float coef = sqrtf(s2 / s6);
    #pragma unroll
    for (int i = 0; i < 8; ++i) {
      float f = yv[i] * coef;
      ksum_acc[i] += f;
      kfT[(d0 + i) * 40 + sp] = f2bfu(f);
    }
    if (isbf) {
      uint4 u = *(const uint4*)((const unsigned short*)values + gi);
      unsigned short vs[8];
      *(uint4*)vs = u;
      #pragma unroll
      for (int i = 0; i < 8; ++i) vvT[(d0 + i) * 40 + sp] = vs[i];
    } else {
      float vraw[8];
      load8(values, gi, 0, vraw);
      #pragma unroll
      for (int i = 0; i < 8; ++i) vvT[(d0 + i) * 40 + sp] = f2bfu(vraw[i]);
    }
    __syncthreads();

    const int v = wid * 16 + m16;
    short8 bfr = *(const short8*)&vvT[v * 40 + (quad ^ ((v >> 3) & 3)) * 8];
    #pragma unroll
    for (int mt = 0; mt < 4; ++mt) {
      int d = mt * 16 + m16;
      short8 afr = *(const short8*)&kfT[d * 40 + (quad ^ ((d >> 3) & 3)) * 8];
      acc[mt] = __builtin_amdgcn_mfma_f32_16x16x32_bf16(afr, bfr, acc[mt], 0, 0, 0);
    }
    __syncthreads();
  }

  // fp32 partials: kv_p[chunk][nh][d][v]
  float* dst = kv_p + ((size_t)chunk * 64 + nh) * 4096;
  #pragma unroll
  for (int mt = 0; mt < 4; ++mt)
    #pragma unroll
    for (int rr = 0; rr < 4; ++rr) {
      int d = mt * 16 + quad * 4 + rr;
      dst[d * 64 + wid * 16 + m16] = acc[mt][rr];
    }

  // ksum: reduce across row-groups (masks 8,16,32), then block reduce + atomic
  #pragma unroll
  for (int i = 0; i < 8; ++i) {
    #pragma unroll
    for (int m = 8; m < 64; m <<= 1) ksum_acc[i] += __shfl_xor(ksum_acc[i], m, 64);
  }
  if (r == 0) {
    #pragma unroll
    for (int i = 0; i < 8; ++i) red[wid * 64 + d0 + i] = ksum_acc[i];
  }
  __syncthreads();
  if (t < 64) {
    float tot = red[t] + red[64 + t] + red[128 + t] + red[192 + t];
    atomicAdd(&ksum_g[nh * 64 + t], tot);
  }
}

// ---------- reduce: sum chunks, emit kv bf16 [nh][v][d] ----------
__global__ __launch_bounds__(256) void reduce_kernel(
    const float* __restrict__ kv_p, unsigned short* __restrict__ kvb, int chunks)
{
  int cidx = blockIdx.x * 256 + threadIdx.x;   // 0..262143
  int nh = cidx >> 12;
  int dv = cidx & 4095;
  int d = dv >> 6, v = dv & 63;
  float s = 0.f;
  for (int ch = 0; ch < chunks; ++ch)
    s += kv_p[((size_t)ch * 64 + nh) * 4096 + dv];
  kvb[(nh * 64 + v) * 64 + d] = f2bfu(s);
}

// ---------- attention kernel: per (n,h,y) MFMA O = (qf*z) @ kv ----------
__global__ __launch_bounds__(256) void attn_kernel(
    const void* __restrict__ queries, const unsigned short* __restrict__ kvb,
    const float* __restrict__ ksum_g, const void* __restrict__ scale_param,
    void* __restrict__ out, const int* __restrict__ flagp)
{
  __shared__ __align__(16) unsigned short qf[64 * 72];  // stride 36 dwords

  const int isbf = *flagp;
  const int b = blockIdx.x;
  const int y = b & 63;
  const int nh = b >> 6;
  const int h = nh & 7, n = nh >> 3;
  const int t = threadIdx.x, lane = t & 63, wid = t >> 6;
  const int quad = lane >> 4, m16 = lane & 15;
  const int r = lane >> 3, c = lane & 7, d0 = c * 8;

  float inv_s[8];
  #pragma unroll
  for (int i = 0; i < 8; ++i) inv_s[i] = softplus_inv(ldf(scale_param, d0 + i, isbf));
  float ks[8];
  {
    float4 k0 = *(const float4*)&ksum_g[nh * 64 + d0];
    float4 k1 = *(const float4*)&ksum_g[nh * 64 + d0 + 4];
    ks[0]=k0.x; ks[1]=k0.y; ks[2]=k0.z; ks[3]=k0.w;
    ks[4]=k1.x; ks[5]=k1.y; ks[6]=k1.z; ks[7]=k1.w;
  }

  // B fragments from global (L2-resident)
  const unsigned short* kvrow = kvb + (nh * 64 + wid * 16 + m16) * 64;
  short8 bfr0 = *(const short8*)&kvrow[quad * 8];
  short8 bfr1 = *(const short8*)&kvrow[32 + quad * 8];

  // stage qf: wave wid covers x = wid*16..+15 in 2 batches of 8 rows
  #pragma unroll
  for (int batch = 0; batch < 2; ++batch) {
    int x = wid * 16 + batch * 8 + r;
    int gi = ((n * LSEQ + y * 64 + x) * NHEAD + h) * DCH + d0;
    float qraw[8];
    load8(queries, gi, isbf, qraw);
    float xv[8], yv[8], s2 = 0.f, s6 = 0.f;
    #pragma unroll
    for (int i = 0; i < 8; ++i) {
      xv[i] = (fmaxf(qraw[i], 0.f) + 1e-6f) * inv_s[i];
      s2 += xv[i] * xv[i];
    }
    #pragma unroll
    for (int i = 0; i < 8; ++i) {
      yv[i] = xv[i] * xv[i] * xv[i];
      s6 += yv[i] * yv[i];
    }
    row_reduce2(s2, s6);
    const float coef = sqrtf(s2 / s6);
    float f[8], dot = 0.f;
    #pragma unroll
    for (int i = 0; i < 8; ++i) { f[i] = yv[i] * coef; dot += f[i] * ks[i]; }
    dot = row_reduce1(dot);
    const float z = 1.f / (dot + 1e-6f);
    uint4 pk;
    pk.x = (unsigned int)f2bfu(f[0] * z) | ((unsigned int)f2bfu(f[1] * z) << 16);
    pk.y = (unsigned int)f2bfu(f[2] * z) | ((unsigned int)f2bfu(f[3] * z) << 16);
    pk.z = (unsigned int)f2bfu(f[4] * z) | ((unsigned int)f2bfu(f[5] * z) << 16);
    pk.w = (unsigned int)f2bfu(f[6] * z) | ((unsigned int)f2bfu(f[7] * z) << 16);
    *(uint4*)&qf[x * 72 + d0] = pk;
  }
  __syncthreads();

  const size_t obase = (((size_t)n * LSEQ + y * 64) * NHEAD + h) * DCH;
  #pragma unroll
  for (int mt = 0; mt < 4; ++mt) {
    f32x4 acc = (f32x4){0.f, 0.f, 0.f, 0.f};
    short8 a0 = *(const short8*)&qf[(mt * 16 + m16) * 72 + quad * 8];
    short8 a1 = *(const short8*)&qf[(mt * 16 + m16) * 72 + 32 + quad * 8];
    acc = __builtin_amdgcn_mfma_f32_16x16x32_bf16(a0, bfr0, acc, 0, 0, 0);
    acc = __builtin_amdgcn_mfma_f32_16x16x32_bf16(a1, bfr1, acc, 0, 0, 0);
    #pragma unroll
    for (int rr = 0; rr < 4; ++rr) {
      int x = mt * 16 + quad * 4 + rr;
      int v = wid * 16 + m16;
      size_t oi = obase + (size_t)x * (NHEAD * DCH) + v;
      if (isbf) ((unsigned short*)out)[oi] = f2bfu(acc[rr]);
      else      ((float*)out)[oi] = acc[rr];
    }
  }
}

// ---------- conv kernel: depthwise 5x5 + bias, RMW on out ----------
__global__ __launch_bounds__(256) void conv_kernel(
    const void* __restrict__ values, const void* __restrict__ dwc_w,
    const void* __restrict__ dwc_b, void* __restrict__ out,
    const int* __restrict__ flagp)
{
  __shared__ __align__(16) unsigned short vs[8 * 64 * 64];  // 64 KB
  __shared__ float wl[25 * 64];
  __shared__ float bl[64];

  const int isbf = *flagp;
  const int b = blockIdx.x;
  const int slab = b & 15;
  const int nh = b >> 4;
  const int h = nh & 7, n = nh >> 3;
  const int y0 = slab * 4;
  const int t = threadIdx.x;

  for (int i = t; i < 25 * 64; i += 256) {
    int d = i / 25, tap = i - d * 25;
    wl[tap * 64 + d] = ldf(dwc_w, i, isbf);
  }
  if (t < 64) bl[t] = ldf(dwc_b, t, isbf);

  for (int it = t; it < 8 * 64 * 8; it += 256) {
    int j = it & 7;
    int xx = (it >> 3) & 63;
    int rr = it >> 9;
    int yy = y0 - 2 + rr;
    unsigned short* dst = &vs[((rr * 64 + xx) * 64) + ((j ^ (xx & 7)) * 8)];
    if (yy >= 0 && yy < HEIGHT) {
      int gi = ((n * LSEQ + yy * 64 + xx) * NHEAD + h) * DCH + j * 8;
      if (isbf) {
        *(uint4*)dst = *(const uint4*)((const unsigned short*)values + gi);
      } else {
        const float4* s4 = (const float4*)((const float*)values + gi);
        float4 f0 = s4[0], f1 = s4[1];
        dst[0] = f2bfu(f0.x); dst[1] = f2bfu(f0.y);
        dst[2] = f2bfu(f0.z); dst[3] = f2bfu(f0.w);
        dst[4] = f2bfu(f1.x); dst[5] = f2bfu(f1.y);
        dst[6] = f2bfu(f1.z); dst[7] = f2bfu(f1.w);
      }
    } else {
      uint4 z; z.x = z.y = z.z = z.w = 0u;
      *(uint4*)dst = z;
    }
  }
  __syncthreads();

  const int xx = t & 63, jb = t >> 6;
  for (int jj = jb; jj < 8; jj += 4) {
    float a[4][8];
    float bias8[8];
    {
      float4 b0 = *(const float4*)&bl[jj * 8];
      float4 b1 = *(const float4*)&bl[jj * 8 + 4];
      bias8[0]=b0.x; bias8[1]=b0.y; bias8[2]=b0.z; bias8[3]=b0.w;
      bias8[4]=b1.x; bias8[5]=b1.y; bias8[6]=b1.z; bias8[7]=b1.w;
    }
    #pragma unroll
    for (int rr = 0; rr < 4; ++rr)
      #pragma unroll
      for (int cc = 0; cc < 8; ++cc) a[rr][cc] = bias8[cc];

    for (int ky = 0; ky < 5; ++ky) {
      #pragma unroll
      for (int kx = 0; kx < 5; ++kx) {
        int xs = xx + kx - 2;
        if ((unsigned)xs < (unsigned)WIDTH) {
          float4 w0 = *(const float4*)&wl[(ky * 5 + kx) * 64 + jj * 8];
          float4 w1 = *(const float4*)&wl[(ky * 5 + kx) * 64 + jj * 8 + 4];
          #pragma unroll
          for (int rr = 0; rr < 4; ++rr) {
            uint4 pv = *(const uint4*)&vs[(((rr + ky) * 64 + xs) * 64) + ((jj ^ (xs & 7)) * 8)];
            float v0,v1,v2,v3,v4,v5,v6,v7;
            unpack2(pv.x, v0, v1); unpack2(pv.y, v2, v3);
            unpack2(pv.z, v4, v5); unpack2(pv.w, v6, v7);
            a[rr][0] += w0.x * v0; a[rr][1] += w0.y * v1;
            a[rr][2] += w0.z * v2; a[rr][3] += w0.w * v3;
            a[rr][4] += w1.x * v4; a[rr][5] += w1.y * v5;
            a[rr][6] += w1.z * v6; a[rr][7] += w1.w * v7;
          }
        }
      }
    }
    #pragma unroll
    for (int rr = 0; rr < 4; ++rr) {
      size_t oi = (((size_t)n * LSEQ + (y0 + rr) * 64 + xx) * NHEAD + h) * DCH + jj * 8;
      if (isbf) {
        unsigned short* op = (unsigned short*)out + oi;
        uint4 cur = *(uint4*)op;
        float c0,c1,c2,c3,c4,c5,c6,c7;
        unpack2(cur.x, c0, c1); unpack2(cur.y, c2, c3);
        unpack2(cur.z, c4, c5); unpack2(cur.w, c6, c7);
        uint4 res;
        res.x = (unsigned int)f2bfu(c0 + a[rr][0]) | ((unsigned int)f2bfu(c1 + a[rr][1]) << 16);
        res.y = (unsigned int)f2bfu(c2 + a[rr][2]) | ((unsigned int)f2bfu(c3 + a[rr][3]) << 16);
        res.z = (unsigned int)f2bfu(c4 + a[rr][4]) | ((unsigned int)f2bfu(c5 + a[rr][5]) << 16);
        res.w = (unsigned int)f2bfu(c6 + a[rr][6]) | ((unsigned int)f2bfu(c7 + a[rr][7]) << 16);
        *(uint4*)op = res;
      } else {
        float* op = (float*)out + oi;
        float4 o0 = *(float4*)op;
        float4 o1 = *(float4*)(op + 4);
        o0.x += a[rr][0]; o0.y += a[rr][1]; o0.z += a[rr][2]; o0.w += a[rr][3];
        o1.x += a[rr][4]; o1.y += a[rr][5]; o1.z += a[rr][6]; o1.w += a[rr][7];
        *(float4*)op = o0;
        *(float4*)(op + 4) = o1;
      }
    }
  }
}

// ---------- launch ----------
extern "C" void kernel_launch(void* const* d_in, const int* in_sizes, int n_in,
                              void* d_out, int out_size, void* d_ws, size_t ws_size,
                              hipStream_t stream) {
  int chunks = 16;
  while (chunks > 1) {
    size_t need = (size_t)chunks * 64 * 4096 * 4 + 64 * 4096 * 2 + 4096 * 4 + 64;
    if (need <= ws_size) break;
    chunks >>= 1;
  }
  const int rows = LSEQ / chunks;

  float* kv_p = (float*)d_ws;
  unsigned short* kvb = (unsigned short*)(kv_p + (size_t)chunks * 64 * 4096);
  float* ksum = (float*)(kvb + 64 * 4096);
  int* flag = (int*)(ksum + 4096);

  hipMemsetAsync(ksum, 0, 4096 * sizeof(float), stream);
  detect_kernel<<<1, 64, 0, stream>>>((const unsigned int*)d_in[0], flag);
  kv_kernel<<<64 * chunks, 256, 0, stream>>>(
      d_in[1], d_in[2], d_in[3], kv_p, ksum, flag, chunks, rows);
  reduce_kernel<<<1024, 256, 0, stream>>>(kv_p, kvb, chunks);
  attn_kernel<<<4096, 256, 0, stream>>>(
      d_in[0], kvb, ksum, d_in[3], d_out, flag);
  conv_kernel<<<64 * 16, 256, 0, stream>>>(
      d_in[2], d_in[4], d_in[5], d_out, flag);
}